// Round 9
// baseline (291.044 us; speedup 1.0000x reference)
//
#include <hip/hip_runtime.h>
#include <cstdint>

// ShortTermLSTM on MI355X: batched LSTM, transposed-GEMM f16 MFMA, cell fully
// in registers, fused-rcp activations in the exp2 domain (raw v_exp_f32).
// Plateau ledger: R15 251 / R16 269 / R17 262 / R18 256 / R21 250.
// R21 falsified occupancy (26->38%, wall flat). All throughput pipes slack
// (MFMA 29, VALU 59 (mostly trans@16cyc), LDS ~40%, HBM 1%); per-step wall
// ~3100 cyc vs ~1000 issue estimate -> barrier max-term / latency bound.
// Last untested max-term: the PER-STEP GLOBAL x-LOAD (L3 latency 600-900)
// drained inside every step on the refresh waves.
// R22 (this): pre-stage ALL x into LDS once (s_X, 32KB, coalesced float4 +
// f16 hi/lo convert at init); step loop becomes pure LDS (refresh = 1
// ds_read_u16 + 1-2 ds_write_b16, ~120 cyc). + s_setprio(1) around compute
// (wave role diversity: heavy/light/refresh -> T5 regime).
// Geometry (R21): 768 blocks x 512 thr x 16 seqs; wave w owns pair w (tiles
// 2w,2w+1, all kc in 32 AGPR); waves 0-3 + pair 8+w from s_W; wave 4 tile24;
// waves 5,6 refresh. One barrier/step. LDS 78,336 B; 2 blocks/CU.
// Pair-tile layout (tile<24): tileA rows {i(u0),i(u1),f(u0),f(u1)} x4 quads,
// tileB {g,g,o,o}; u0 = 8*pair + 2*quad, u1 = u0+1. acc A=(i0,i1,f0,f1),
// B=(g0,g1,o0,o1) -> v_pk_*_f32 activation; ds_write_b32 h per pair.
// k-map identity for h (k=u); x/bias k100..113.
// Residual error: dropped h*W_hh_lo (~6e-5/step); measured margin ~4x.

#define H_UNITS 100
#define T_STEPS 128
#define S_BLK   16
#define NSEQ    12288
#define NBLK    (NSEQ / S_BLK)   // 768
#define NTILE   25               // 100 units / 4 rows-of-4 per tile
#define KSTR    136              // LDS h row stride (ushorts)
#define LOG2E   1.4426950408889634f
#define TWO_L   2.8853900817779268f   // 2*log2(e)

typedef __attribute__((ext_vector_type(8))) _Float16 halfx8;
typedef __attribute__((ext_vector_type(8))) unsigned short ushortx8;
typedef __attribute__((ext_vector_type(4))) float floatx4;
typedef __attribute__((ext_vector_type(2))) float floatx2;

__device__ __forceinline__ unsigned short f32_to_f16u(float x) {
    _Float16 h = (_Float16)x;                       // v_cvt_f16_f32 (RNE)
    return __builtin_bit_cast(unsigned short, h);
}
__device__ __forceinline__ float f16u_to_f32(unsigned short u) {
    _Float16 h = __builtin_bit_cast(_Float16, u);
    return (float)h;
}
#if __has_builtin(__builtin_amdgcn_exp2f)
__device__ __forceinline__ float fexp2(float x) { return __builtin_amdgcn_exp2f(x); }
#else
__device__ __forceinline__ float fexp2(float x) { return exp2f(x); }
#endif

// ---------------------------------------------------------------------------
// Prep: pack W (pre-scaled into exp2 domain) into MFMA A-operand fragments.
// Pair-tile row map (tile<24): pr=tile>>1, half=tile&1, reg=m&3, qr=m>>2:
//   gate = (reg>>1) + 2*half   (A: i,f ; B: g,o)
//   unit = 8*pr + 2*qr + (reg&1)
//   n = gate*100 + unit        (torch gate order i,f,g,o)
// Tile 24: n = (m&3)*100 + 96 + (m>>2)  (i,f,g,o-per-quad layout).
// k-map: identity for h (k<100); x/bias cols:
//   k100..103 x_hi(W_hi); k104..107 x_lo(W_hi); k108..111 x_hi(W_lo);
//   k112/113 bias hi/lo (A=1.0); k114..127 zero.
// ---------------------------------------------------------------------------
__global__ void lstm_prep_pack(const float* __restrict__ W_ih,
                               const float* __restrict__ W_hh,
                               const float* __restrict__ b_ih,
                               const float* __restrict__ b_hh,
                               ushortx8* __restrict__ Bpack) {
    int t = blockIdx.x * 256 + threadIdx.x;   // (tile,kc,lane): 25*4*64 = 6400
    if (t >= NTILE * 4 * 64) return;
    int lane = t & 63;
    int kc   = (t >> 6) & 3;
    int tile = t >> 8;
    int m    = lane & 15;
    int n;
    if (tile < 24) {
        int pr = tile >> 1, half = tile & 1;
        int reg = m & 3,   qr   = m >> 2;
        int g = (reg >> 1) + 2 * half;
        int u = 8 * pr + 2 * qr + (reg & 1);
        n = g * 100 + u;
    } else {
        n = (m & 3) * 100 + 96 + (m >> 2);
    }
    float sc = (n >= 200 && n < 300) ? (2.0f * LOG2E) : LOG2E;   // g rows get 2x
    int k0 = kc * 32 + ((lane >> 4) & 3) * 8;
    ushortx8 v;
#pragma unroll
    for (int j = 0; j < 8; ++j) {
        int k = k0 + j;
        unsigned short w = 0;
        if (k < 100) {
            w = f32_to_f16u(W_hh[n * 100 + k] * sc);             // identity k-map
        } else if (k < 108) {
            w = f32_to_f16u(W_ih[n * 4 + ((k - 100) & 3)] * sc); // hi W (x_hi & x_lo)
        } else if (k < 112) {
            float wf = W_ih[n * 4 + (k - 108)] * sc;             // lo W (x_hi)
            unsigned short hi = f32_to_f16u(wf);
            w = f32_to_f16u(wf - f16u_to_f32(hi));
        } else if (k == 112) {
            float bb = (b_ih[n] + b_hh[n]) * sc;                 // b_hi (A=1.0)
            w = f32_to_f16u(bb);
        } else if (k == 113) {
            float bb = (b_ih[n] + b_hh[n]) * sc;                 // b_lo (A=1.0)
            unsigned short hi = f32_to_f16u(bb);
            w = f32_to_f16u(bb - f16u_to_f32(hi));
        }
        v[j] = w;
    }
    Bpack[t] = v;
}

// ---------------------------------------------------------------------------
// Main: one block = 16 sequences, 8 waves, full T loop.
// Wave w: own pair p0=w (tiles 2w,2w+1, all kc in regs).
//   w<4 : second pair p1=8+w (tiles 16+2w,17+2w) with W from s_W.
//   w==4: tile 24 (units 96..99) with W from s_W.
//   w in {5,6}: x-refresh threads (tids 320..447) — now pure LDS via s_X.
// s_W frag f: f<32 -> tile 16+(f>>2), kc=f&3 ; f in 32..35 -> tile24 kc=f-32.
// s_X[t][s][0..7] = (x_hi[0..3], x_lo[0..3]) per seq/step, filled at init.
// One barrier per step.
// ---------------------------------------------------------------------------
__global__ void __launch_bounds__(512, 4)
lstm_main(const float* __restrict__ x, const ushortx8* __restrict__ Bpack,
          float* __restrict__ out) {
    __shared__ __align__(16) unsigned short s_A[2][16 * KSTR];   // ping-pong, 8,704 B
    __shared__ __align__(16) ushortx8       s_W[36 * 64];        // 36,864 B
    __shared__ __align__(16) ushortx8       s_X[T_STEPS * 16];   // 32,768 B

    const int tid  = threadIdx.x;
    const int lane = tid & 63;
    const int wavu = __builtin_amdgcn_readfirstlane(tid >> 6);   // 0..7
    const int seq0 = blockIdx.x * S_BLK;
    const int m    = lane & 15;
    const int quad = lane >> 4;
    const int q2   = quad << 1;

    // ---- own-pair W fragments, all kc in regs (8 frags = 32 regs)
    halfx8 wfA[4], wfB[4];
#pragma unroll
    for (int kc = 0; kc < 4; ++kc) {
        wfA[kc] = __builtin_bit_cast(halfx8, Bpack[((2 * wavu) * 4 + kc) * 64 + lane]);
        wfB[kc] = __builtin_bit_cast(halfx8, Bpack[((2 * wavu + 1) * 4 + kc) * 64 + lane]);
    }

    // ---- LDS weight staging: tiles 16..23 (all kc) + tile 24 (all kc)
    for (int i = tid; i < 36 * 64; i += 512) {
        int f = i >> 6, ln = i & 63;
        int tile = (f < 32) ? (16 + (f >> 2)) : 24;
        int kc   = (f < 32) ? (f & 3) : (f - 32);
        s_W[i] = Bpack[(tile * 4 + kc) * 64 + ln];
    }

    // ---- x staging: block's slice (16 seqs x 128 t x 4 f) -> f16 hi/lo pairs
    // s_X[t*16 + s] = {hi0,hi1,hi2,hi3, lo0,lo1,lo2,lo3}
    {
        const float4* xg = (const float4*)(x + (size_t)seq0 * (T_STEPS * 4));
        for (int i = tid; i < 16 * T_STEPS; i += 512) {   // i = s*128 + t
            float4 v = xg[i];
            const float* vf = (const float*)&v;
            int s = i >> 7, tt = i & 127;
            ushortx8 pk;
#pragma unroll
            for (int j = 0; j < 4; ++j) {
                unsigned short hi = f32_to_f16u(vf[j]);
                pk[j]     = hi;
                pk[4 + j] = f32_to_f16u(vf[j] - f16u_to_f32(hi));
            }
            s_X[tt * 16 + s] = pk;
        }
    }

    // refresh mapping (tids 320..447): 16 seqs x 8 cols
    const int rt   = tid - 320;
    const bool refr = (rt >= 0) && (rt < 128);
    const int rtc  = refr ? rt : 0;
    const int rs   = rtc & 15, rc = (rtc >> 4) & 7;
    const unsigned short* sxp = (const unsigned short*)s_X;

    // ---- zero both buffers (h(0)=0; k114..127 stay 0 forever)
    for (int i = tid; i < (2 * 16 * KSTR) / 2; i += 512)
        ((unsigned int*)s_A)[i] = 0u;
    __syncthreads();   // s_X + zeroed s_A visible

    // ---- x(t=0) into buf0 (from s_X); constant bias cols into BOTH buffers
    if (refr) {
        unsigned short v = sxp[rs * 8 + rc];     // t=0 slot
        if (rc < 4) {
            s_A[0][rs * KSTR + 100 + rc] = v;    // x_hi (W_hi)
            s_A[0][rs * KSTR + 108 + rc] = v;    // x_hi (W_lo)
        } else {
            s_A[0][rs * KSTR + 104 + (rc - 4)] = v;   // x_lo (W_hi)
        }
    } else if (tid < 64) {
        // 64 writes: 2 bufs x 16 rows x 2 bias cols (k112,k113) = 1.0
        int b = tid >> 5, r = (tid >> 1) & 15, col = 112 + (tid & 1);
        s_A[b][r * KSTR + col] = 0x3C00;
    }
    __syncthreads();   // init writes visible before first read

    floatx2 c0 = {0.0f, 0.0f};    // own pair cell state (2*log2e domain)
    floatx2 c1 = {0.0f, 0.0f};    // second pair (waves 0..3)
    float   c24 = 0.0f;           // tile 24 (wave 4)

    const int rowOff = m * KSTR;
    const int aOff   = rowOff + quad * 8;
    const int hb     = wavu * 512 + lane;    // s_W heavy-pair base (A at +0, B at +256)

    for (int t = 0; t < T_STEPS; ++t) {
        const int bR = t & 1;
        const unsigned short* base  = s_A[bR];
        unsigned short*       baseW = s_A[bR ^ 1];

        halfx8 hh[4];
#pragma unroll
        for (int kc = 0; kc < 4; ++kc)
            hh[kc] = *(const halfx8*)(base + aOff + kc * 32);   // ds_read_b128

        const bool last = (t == T_STEPS - 1);

        auto gemm4 = [&](halfx8 w0, halfx8 w1, halfx8 w2, halfx8 w3) {
            floatx4 a = {0.0f, 0.0f, 0.0f, 0.0f};
            a = __builtin_amdgcn_mfma_f32_16x16x32_f16(w0, hh[0], a, 0, 0, 0);
            a = __builtin_amdgcn_mfma_f32_16x16x32_f16(w1, hh[1], a, 0, 0, 0);
            a = __builtin_amdgcn_mfma_f32_16x16x32_f16(w2, hh[2], a, 0, 0, 0);
            a = __builtin_amdgcn_mfma_f32_16x16x32_f16(w3, hh[3], a, 0, 0, 0);
            return a;
        };

        // packed 2-cell activation: accA=(i0,i1,f0,f1), accB=(g0,g1,o0,o1)
        auto activatePair = [&](floatx4 aA, floatx4 aB, floatx2& cm, int p) {
            floatx2 ei = {fexp2(aA[0]), fexp2(aA[1])};   // e^i
            floatx2 ef = {fexp2(aA[2]), fexp2(aA[3])};   // e^f
            floatx2 eg = {fexp2(aB[0]), fexp2(aB[1])};   // e^{2g}
            floatx2 eo = {fexp2(aB[2]), fexp2(aB[3])};   // e^o
            floatx2 a  = ei + 1.0f;                      // v_pk_add_f32
            floatx2 b  = ef + 1.0f;
            floatx2 d  = eg + 1.0f;
            floatx2 p1 = eo + 1.0f;
            floatx2 e2s = eg * TWO_L - TWO_L;            // v_pk_fma_f32
            floatx2 q  = a * d;
            floatx2 qb = q * b;
            floatx2 r  = {__builtin_amdgcn_rcpf(qb[0]), __builtin_amdgcn_rcpf(qb[1])};
            floatx2 eib = ei * b;
            floatx2 efq = ef * q;
            floatx2 tt  = eib * e2s;
            floatx2 nm  = efq * cm + tt;                 // v_pk_fma_f32
            floatx2 c2  = nm * r;
            cm = c2;
            floatx2 cc = {fminf(c2[0], 115.0f), fminf(c2[1], 115.0f)};
            floatx2 ec = {fexp2(cc[0]), fexp2(cc[1])};   // e^{2c}
            floatx2 p2 = ec + 1.0f;
            floatx2 nu = ec - 1.0f;
            floatx2 pp = p1 * p2;
            floatx2 r2 = {__builtin_amdgcn_rcpf(pp[0]), __builtin_amdgcn_rcpf(pp[1])};
            floatx2 eon = eo * nu;
            floatx2 hv  = eon * r2;
            if (!last) {
                unsigned int pk = (unsigned int)f32_to_f16u(hv[0]) |
                                  ((unsigned int)f32_to_f16u(hv[1]) << 16);
                *(unsigned int*)&baseW[rowOff + 8 * p + q2] = pk;   // ds_write_b32
            } else {
                *(floatx2*)&out[(size_t)(seq0 + m) * H_UNITS + 8 * p + q2] = hv;
            }
        };

        __builtin_amdgcn_s_setprio(1);           // favor compute cluster (T5)
        // ---- own pair (W in regs)
        {
            floatx4 aA = gemm4(wfA[0], wfA[1], wfA[2], wfA[3]);
            floatx4 aB = gemm4(wfB[0], wfB[1], wfB[2], wfB[3]);
            activatePair(aA, aB, c0, wavu);
        }

        if (wavu < 4) {
            // ---- second pair p1 = 8+wavu (tiles 16+2w / 17+2w), W from LDS
            halfx8 wa0 = __builtin_bit_cast(halfx8, s_W[hb + 0 * 64]);
            halfx8 wa1 = __builtin_bit_cast(halfx8, s_W[hb + 1 * 64]);
            halfx8 wa2 = __builtin_bit_cast(halfx8, s_W[hb + 2 * 64]);
            halfx8 wa3 = __builtin_bit_cast(halfx8, s_W[hb + 3 * 64]);
            floatx4 aA = gemm4(wa0, wa1, wa2, wa3);
            halfx8 wb0 = __builtin_bit_cast(halfx8, s_W[hb + 256 + 0 * 64]);
            halfx8 wb1 = __builtin_bit_cast(halfx8, s_W[hb + 256 + 1 * 64]);
            halfx8 wb2 = __builtin_bit_cast(halfx8, s_W[hb + 256 + 2 * 64]);
            halfx8 wb3 = __builtin_bit_cast(halfx8, s_W[hb + 256 + 3 * 64]);
            floatx4 aB = gemm4(wb0, wb1, wb2, wb3);
            activatePair(aA, aB, c1, 8 + wavu);
        } else if (wavu == 4) {
            // ---- tile 24 (units 96..99), W from LDS, scalar activation
            halfx8 w0 = __builtin_bit_cast(halfx8, s_W[2048 + 0 * 64 + lane]);
            halfx8 w1 = __builtin_bit_cast(halfx8, s_W[2048 + 1 * 64 + lane]);
            halfx8 w2 = __builtin_bit_cast(halfx8, s_W[2048 + 2 * 64 + lane]);
            halfx8 w3 = __builtin_bit_cast(halfx8, s_W[2048 + 3 * 64 + lane]);
            floatx4 acc = gemm4(w0, w1, w2, w3);
            float ei = fexp2(acc[0]);
            float ef = fexp2(acc[1]);
            float eg = fexp2(acc[2]);
            float eo = fexp2(acc[3]);
            float a  = 1.0f + ei, b = 1.0f + ef;
            float d  = eg + 1.0f;
            float e2s = fmaf(eg, TWO_L, -TWO_L);
            float q  = a * d;
            float r  = __builtin_amdgcn_rcpf(q * b);
            float nm = fmaf(ef * q, c24, (ei * b) * e2s);
            float c2 = nm * r;
            c24 = c2;
            float cc = fminf(c2, 115.0f);
            float ec = fexp2(cc);
            float r2 = __builtin_amdgcn_rcpf((1.0f + eo) * (ec + 1.0f));
            float h  = (eo * (ec - 1.0f)) * r2;
            if (!last) {
                baseW[rowOff + 96 + quad] = f32_to_f16u(h);        // k = unit
            } else {
                out[(size_t)(seq0 + m) * H_UNITS + 96 + quad] = h;
            }
        }
        __builtin_amdgcn_s_setprio(0);

        if (refr && !last) {                     // x(t+1) -> other buffer (pure LDS)
            unsigned short v = sxp[(t + 1) * 128 + rs * 8 + rc];
            if (rc < 4) {
                baseW[rs * KSTR + 100 + rc] = v;
                baseW[rs * KSTR + 108 + rc] = v;
            } else {
                baseW[rs * KSTR + 104 + (rc - 4)] = v;
            }
        }
        __syncthreads();   // single barrier/step: covers both cross-step hazards
    }
}

extern "C" void kernel_launch(void* const* d_in, const int* in_sizes, int n_in,
                              void* d_out, int out_size, void* d_ws, size_t ws_size,
                              hipStream_t stream) {
    const float* x    = (const float*)d_in[0];   // [4096,3,128,4]
    const float* W_ih = (const float*)d_in[1];   // [400,4]
    const float* W_hh = (const float*)d_in[2];   // [400,100]
    const float* b_ih = (const float*)d_in[3];   // [400]
    const float* b_hh = (const float*)d_in[4];   // [400]
    ushortx8* Bpack = (ushortx8*)d_ws;           // 25*4*64*16 B = 102,400 B

    lstm_prep_pack<<<25, 256, 0, stream>>>(W_ih, W_hh, b_ih, b_hh, Bpack);
    lstm_main<<<NBLK, 512, 0, stream>>>(x, Bpack, (float*)d_out);
}